// Round 2
// baseline (2142.674 us; speedup 1.0000x reference)
//
#include <hip/hip_runtime.h>
#include <math.h>

#define NUM_USERS 100000
#define NUM_ITEMS 50000
#define N_NODES   (NUM_USERS + NUM_ITEMS)
#define DIM       64
#define NNZ_      3200000
#define BATCH_    4096

// embedding of node `node`, component `lane`, from the two concatenated tables
__device__ __forceinline__ float emb0(const float* __restrict__ ue,
                                      const float* __restrict__ ie,
                                      int node, int lane) {
    return (node < NUM_USERS) ? ue[(long long)node * DIM + lane]
                              : ie[(long long)(node - NUM_USERS) * DIM + lane];
}

// hop 1: gather from the concatenated input embeddings
__global__ void spmm_first(const int* __restrict__ erow, const int* __restrict__ ecol,
                           const float* __restrict__ eval_,
                           const float* __restrict__ ue, const float* __restrict__ ie,
                           float* __restrict__ out) {
    long long t = (long long)blockIdx.x * blockDim.x + threadIdx.x;
    int e    = (int)(t >> 6);
    int lane = (int)(t & 63);
    if (e >= NNZ_) return;
    int   c = ecol[e];
    int   r = erow[e];
    float v = eval_[e];
    float xv = emb0(ue, ie, c, lane);
    atomicAdd(&out[(long long)r * DIM + lane], v * xv);
}

// hops 2..3: gather from previous hop's buffer
__global__ void spmm_next(const int* __restrict__ erow, const int* __restrict__ ecol,
                          const float* __restrict__ eval_,
                          const float* __restrict__ x, float* __restrict__ out) {
    long long t = (long long)blockIdx.x * blockDim.x + threadIdx.x;
    int e    = (int)(t >> 6);
    int lane = (int)(t & 63);
    if (e >= NNZ_) return;
    int   c = ecol[e];
    int   r = erow[e];
    float v = eval_[e];
    float xv = x[(long long)c * DIM + lane];
    atomicAdd(&out[(long long)r * DIM + lane], v * xv);
}

// one wave per batch element: BPR loss term, atomically accumulated mean
__global__ void score_kernel(const float* __restrict__ ue, const float* __restrict__ ie,
                             const float* __restrict__ b0, const float* __restrict__ b1,
                             const float* __restrict__ b2,
                             const int* __restrict__ users, const int* __restrict__ items,
                             const int* __restrict__ negs,
                             float* __restrict__ out) {
    int t = blockIdx.x * blockDim.x + threadIdx.x;
    int b    = t >> 6;
    int lane = t & 63;
    if (b >= BATCH_) return;

    int un = users[b];                 // user node id in [0, NUM_USERS)
    int in_ = NUM_USERS + items[b];    // item node id in concat space
    int nn  = NUM_USERS + negs[b];

    // acc(node)[lane] = emb0 + hop1 + hop2 + hop3   (light_out = acc/4, folded below)
    long long ou = (long long)un * DIM + lane;
    long long oi = (long long)in_ * DIM + lane;
    long long on = (long long)nn * DIM + lane;
    float u  = emb0(ue, ie, un, lane) + b0[ou] + b1[ou] + b2[ou];
    float it = emb0(ue, ie, in_, lane) + b0[oi] + b1[oi] + b2[oi];
    float ng = emb0(ue, ie, nn, lane) + b0[on] + b1[on] + b2[on];

    float pos = u * it;
    float neg = u * ng;
    #pragma unroll
    for (int s = 32; s >= 1; s >>= 1) {
        pos += __shfl_xor(pos, s);
        neg += __shfl_xor(neg, s);
    }

    if (lane == 0) {
        // scores use light_out = acc/4  ->  dot/16
        float x = (neg - pos) * (1.0f / 16.0f);
        // stable softplus: max(x,0) + log1p(exp(-|x|))
        float sp = fmaxf(x, 0.0f) + log1pf(expf(-fabsf(x)));
        atomicAdd(out, sp * (1.0f / BATCH_));
    }
}

extern "C" void kernel_launch(void* const* d_in, const int* in_sizes, int n_in,
                              void* d_out, int out_size, void* d_ws, size_t ws_size,
                              hipStream_t stream) {
    const int*   edge_row  = (const int*)d_in[0];
    const int*   edge_col  = (const int*)d_in[1];
    const float* edge_val  = (const float*)d_in[2];
    const float* user_emb  = (const float*)d_in[3];
    const float* item_emb  = (const float*)d_in[4];
    const int*   users     = (const int*)d_in[5];
    const int*   items     = (const int*)d_in[6];
    const int*   negatives = (const int*)d_in[7];
    float* out = (float*)d_out;

    const size_t bufElems = (size_t)N_NODES * DIM;   // 9.6M floats = 38.4 MB
    float* b0 = (float*)d_ws;
    float* b1 = b0 + bufElems;
    float* b2 = b1 + bufElems;

    // zero the three hop buffers (atomic accumulation targets) and the output
    hipMemsetAsync(d_ws, 0, 3 * bufElems * sizeof(float), stream);
    hipMemsetAsync(d_out, 0, sizeof(float), stream);

    const int blk = 256;
    const long long totalThreads = (long long)NNZ_ * 64;
    const long long nBlocks = (totalThreads + blk - 1) / blk;   // 800,000 blocks

    spmm_first<<<(dim3)(unsigned)nBlocks, blk, 0, stream>>>(edge_row, edge_col, edge_val,
                                                            user_emb, item_emb, b0);
    spmm_next <<<(dim3)(unsigned)nBlocks, blk, 0, stream>>>(edge_row, edge_col, edge_val, b0, b1);
    spmm_next <<<(dim3)(unsigned)nBlocks, blk, 0, stream>>>(edge_row, edge_col, edge_val, b1, b2);

    score_kernel<<<(BATCH_ * 64) / blk, blk, 0, stream>>>(user_emb, item_emb, b0, b1, b2,
                                                          users, items, negatives, out);
}

// Round 3
// 1255.112 us; speedup vs baseline: 1.7072x; 1.7072x over previous
//
#include <hip/hip_runtime.h>
#include <math.h>

#define NUM_USERS 100000
#define NUM_ITEMS 50000
#define N_NODES   (NUM_USERS + NUM_ITEMS)
#define DIM       64
#define NNZ_      3200000
#define BATCH_    4096

#define SCAN_BLK        256
#define ELEMS_PER_BLOCK 1024
#define NBLK_SCAN       ((N_NODES + ELEMS_PER_BLOCK - 1) / ELEMS_PER_BLOCK)   // 147

// ---------------- CSR build: histogram -> scan -> scatter ----------------

__global__ void hist_rows(const int* __restrict__ erow, int* __restrict__ cnt) {
    int e = blockIdx.x * blockDim.x + threadIdx.x;
    if (e < NNZ_) atomicAdd(&cnt[erow[e]], 1);
}

// per-block sums of 1024-element chunks
__global__ void scan_pass1(const int* __restrict__ cnt, int* __restrict__ bsum) {
    __shared__ int lds[SCAN_BLK];
    int t = threadIdx.x;
    int base = blockIdx.x * ELEMS_PER_BLOCK + t * 4;
    int s = 0;
    #pragma unroll
    for (int i = 0; i < 4; ++i) { int idx = base + i; if (idx < N_NODES) s += cnt[idx]; }
    lds[t] = s;
    __syncthreads();
    for (int off = SCAN_BLK / 2; off >= 1; off >>= 1) {
        if (t < off) lds[t] += lds[t + off];
        __syncthreads();
    }
    if (t == 0) bsum[blockIdx.x] = lds[0];
}

// single-block exclusive scan of the block sums
__global__ void scan_pass2(const int* __restrict__ bsum, int* __restrict__ boff,
                           int* __restrict__ ptr) {
    __shared__ int lds[SCAN_BLK];
    int t = threadIdx.x;
    int v = (t < NBLK_SCAN) ? bsum[t] : 0;
    lds[t] = v;
    __syncthreads();
    for (int off = 1; off < SCAN_BLK; off <<= 1) {
        int add = (t >= off) ? lds[t - off] : 0;
        __syncthreads();
        lds[t] += add;
        __syncthreads();
    }
    if (t < NBLK_SCAN) boff[t] = (t == 0) ? 0 : lds[t - 1];
    if (t == 0) ptr[N_NODES] = NNZ_;   // total is statically known
}

// per-block exclusive scan of counts + block offset -> row pointers
__global__ void scan_pass3(const int* __restrict__ cnt, const int* __restrict__ boff,
                           int* __restrict__ ptr) {
    __shared__ int lds[SCAN_BLK];
    int t = threadIdx.x;
    int base = blockIdx.x * ELEMS_PER_BLOCK + t * 4;
    int c[4]; int s = 0;
    #pragma unroll
    for (int i = 0; i < 4; ++i) { int idx = base + i; c[i] = (idx < N_NODES) ? cnt[idx] : 0; s += c[i]; }
    lds[t] = s;
    __syncthreads();
    for (int off = 1; off < SCAN_BLK; off <<= 1) {
        int add = (t >= off) ? lds[t - off] : 0;
        __syncthreads();
        lds[t] += add;
        __syncthreads();
    }
    int ex = boff[blockIdx.x] + ((t == 0) ? 0 : lds[t - 1]);
    #pragma unroll
    for (int i = 0; i < 4; ++i) {
        int idx = base + i;
        if (idx < N_NODES) { ptr[idx] = ex; ex += c[i]; }
    }
}

// scatter (col, val) pairs into row-sorted order
__global__ void scatter_edges(const int* __restrict__ erow, const int* __restrict__ ecol,
                              const float* __restrict__ eval_, const int* __restrict__ ptr,
                              int* __restrict__ fill, int2* __restrict__ pairs) {
    int e = blockIdx.x * blockDim.x + threadIdx.x;
    if (e >= NNZ_) return;
    int r = erow[e];
    int pos = ptr[r] + atomicAdd(&fill[r], 1);
    pairs[pos] = make_int2(ecol[e], __float_as_int(eval_[e]));
}

// ---------------- CSR SpMM: one wave per row, no atomics ----------------

__global__ void spmm_csr_first(const int* __restrict__ ptr, const int2* __restrict__ pairs,
                               const float* __restrict__ ue, const float* __restrict__ ie,
                               float* __restrict__ out) {
    int w    = (blockIdx.x * blockDim.x + threadIdx.x) >> 6;
    int lane = threadIdx.x & 63;
    if (w >= N_NODES) return;
    int beg = ptr[w], end = ptr[w + 1];
    float acc = 0.f;
    for (int e = beg; e < end; ++e) {
        int2 p = pairs[e];
        const float* base = (p.x < NUM_USERS) ? (ue + (size_t)p.x * DIM)
                                              : (ie + (size_t)(p.x - NUM_USERS) * DIM);
        acc = fmaf(__int_as_float(p.y), base[lane], acc);
    }
    out[(size_t)w * DIM + lane] = acc;
}

__global__ void spmm_csr_next(const int* __restrict__ ptr, const int2* __restrict__ pairs,
                              const float* __restrict__ x, float* __restrict__ out) {
    int w    = (blockIdx.x * blockDim.x + threadIdx.x) >> 6;
    int lane = threadIdx.x & 63;
    if (w >= N_NODES) return;
    int beg = ptr[w], end = ptr[w + 1];
    float acc = 0.f;
    for (int e = beg; e < end; ++e) {
        int2 p = pairs[e];
        acc = fmaf(__int_as_float(p.y), x[(size_t)p.x * DIM + lane], acc);
    }
    out[(size_t)w * DIM + lane] = acc;
}

// ---------------- BPR loss scoring ----------------

__device__ __forceinline__ float emb0(const float* __restrict__ ue,
                                      const float* __restrict__ ie,
                                      int node, int lane) {
    return (node < NUM_USERS) ? ue[(size_t)node * DIM + lane]
                              : ie[(size_t)(node - NUM_USERS) * DIM + lane];
}

__global__ void score_kernel(const float* __restrict__ ue, const float* __restrict__ ie,
                             const float* __restrict__ b0, const float* __restrict__ b1,
                             const float* __restrict__ b2,
                             const int* __restrict__ users, const int* __restrict__ items,
                             const int* __restrict__ negs,
                             float* __restrict__ out) {
    int t = blockIdx.x * blockDim.x + threadIdx.x;
    int b    = t >> 6;
    int lane = t & 63;
    if (b >= BATCH_) return;

    int un  = users[b];
    int in_ = NUM_USERS + items[b];
    int nn  = NUM_USERS + negs[b];

    size_t ou = (size_t)un  * DIM + lane;
    size_t oi = (size_t)in_ * DIM + lane;
    size_t on = (size_t)nn  * DIM + lane;
    float u  = emb0(ue, ie, un,  lane) + b0[ou] + b1[ou] + b2[ou];
    float it = emb0(ue, ie, in_, lane) + b0[oi] + b1[oi] + b2[oi];
    float ng = emb0(ue, ie, nn,  lane) + b0[on] + b1[on] + b2[on];

    float pos = u * it;
    float neg = u * ng;
    #pragma unroll
    for (int s = 32; s >= 1; s >>= 1) {
        pos += __shfl_xor(pos, s);
        neg += __shfl_xor(neg, s);
    }

    if (lane == 0) {
        float x = (neg - pos) * (1.0f / 16.0f);      // light_out = acc/4 -> dot/16
        float sp = fmaxf(x, 0.0f) + log1pf(expf(-fabsf(x)));
        atomicAdd(out, sp * (1.0f / BATCH_));
    }
}

// ---------------- launch ----------------

extern "C" void kernel_launch(void* const* d_in, const int* in_sizes, int n_in,
                              void* d_out, int out_size, void* d_ws, size_t ws_size,
                              hipStream_t stream) {
    const int*   edge_row  = (const int*)d_in[0];
    const int*   edge_col  = (const int*)d_in[1];
    const float* edge_val  = (const float*)d_in[2];
    const float* user_emb  = (const float*)d_in[3];
    const float* item_emb  = (const float*)d_in[4];
    const int*   users     = (const int*)d_in[5];
    const int*   items     = (const int*)d_in[6];
    const int*   negatives = (const int*)d_in[7];
    float* out = (float*)d_out;

    // workspace layout (4-byte units); pairs offset is even -> 8B aligned
    int* w = (int*)d_ws;
    int*  ptr  = w;                                  // N+1 (padded to 150002)
    int*  cnt  = ptr  + 150002;                      // N
    int*  fill = cnt  + N_NODES;                     // N
    int*  bsum = fill + N_NODES;                     // 256
    int*  boff = bsum + 256;                         // 256
    int2* pairs = (int2*)(boff + 256);               // NNZ int2
    float* b0 = (float*)(pairs + NNZ_);
    float* b1 = b0 + (size_t)N_NODES * DIM;
    float* b2 = b1 + (size_t)N_NODES * DIM;

    // zero histogram + fill counters and the scalar output
    hipMemsetAsync(cnt, 0, 2 * (size_t)N_NODES * sizeof(int), stream);
    hipMemsetAsync(d_out, 0, sizeof(float), stream);

    const int blk = 256;
    const int edgeBlocks = (NNZ_ + blk - 1) / blk;            // 12500
    const int rowWaveBlocks = (N_NODES * 64 + blk - 1) / blk; // 37500

    hist_rows   <<<edgeBlocks, blk, 0, stream>>>(edge_row, cnt);
    scan_pass1  <<<NBLK_SCAN, SCAN_BLK, 0, stream>>>(cnt, bsum);
    scan_pass2  <<<1, SCAN_BLK, 0, stream>>>(bsum, boff, ptr);
    scan_pass3  <<<NBLK_SCAN, SCAN_BLK, 0, stream>>>(cnt, boff, ptr);
    scatter_edges<<<edgeBlocks, blk, 0, stream>>>(edge_row, edge_col, edge_val, ptr, fill, pairs);

    spmm_csr_first<<<rowWaveBlocks, blk, 0, stream>>>(ptr, pairs, user_emb, item_emb, b0);
    spmm_csr_next <<<rowWaveBlocks, blk, 0, stream>>>(ptr, pairs, b0, b1);
    spmm_csr_next <<<rowWaveBlocks, blk, 0, stream>>>(ptr, pairs, b1, b2);

    score_kernel<<<(BATCH_ * 64) / blk, blk, 0, stream>>>(user_emb, item_emb, b0, b1, b2,
                                                          users, items, negatives, out);
}

// Round 4
// 747.815 us; speedup vs baseline: 2.8652x; 1.6784x over previous
//
#include <hip/hip_runtime.h>
#include <hip/hip_bf16.h>
#include <math.h>

#define NUM_USERS 100000
#define NUM_ITEMS 50000
#define N_NODES   (NUM_USERS + NUM_ITEMS)
#define DIM       64
#define NNZ_      3200000
#define BATCH_    4096

#define SCAN_BLK        256
#define ELEMS_PER_BLOCK 1024
#define NBLK_SCAN       ((N_NODES + ELEMS_PER_BLOCK - 1) / ELEMS_PER_BLOCK)   // 147

typedef __hip_bfloat16 bf16;

// ---------------- CSR build: histogram -> scan -> scatter ----------------

__global__ void hist_rows(const int* __restrict__ erow, int* __restrict__ cnt) {
    int e = blockIdx.x * blockDim.x + threadIdx.x;
    if (e < NNZ_) atomicAdd(&cnt[erow[e]], 1);
}

__global__ void scan_pass1(const int* __restrict__ cnt, int* __restrict__ bsum) {
    __shared__ int lds[SCAN_BLK];
    int t = threadIdx.x;
    int base = blockIdx.x * ELEMS_PER_BLOCK + t * 4;
    int s = 0;
    #pragma unroll
    for (int i = 0; i < 4; ++i) { int idx = base + i; if (idx < N_NODES) s += cnt[idx]; }
    lds[t] = s;
    __syncthreads();
    for (int off = SCAN_BLK / 2; off >= 1; off >>= 1) {
        if (t < off) lds[t] += lds[t + off];
        __syncthreads();
    }
    if (t == 0) bsum[blockIdx.x] = lds[0];
}

__global__ void scan_pass2(const int* __restrict__ bsum, int* __restrict__ boff,
                           int* __restrict__ ptr) {
    __shared__ int lds[SCAN_BLK];
    int t = threadIdx.x;
    int v = (t < NBLK_SCAN) ? bsum[t] : 0;
    lds[t] = v;
    __syncthreads();
    for (int off = 1; off < SCAN_BLK; off <<= 1) {
        int add = (t >= off) ? lds[t - off] : 0;
        __syncthreads();
        lds[t] += add;
        __syncthreads();
    }
    if (t < NBLK_SCAN) boff[t] = (t == 0) ? 0 : lds[t - 1];
    if (t == 0) ptr[N_NODES] = NNZ_;
}

__global__ void scan_pass3(const int* __restrict__ cnt, const int* __restrict__ boff,
                           int* __restrict__ ptr) {
    __shared__ int lds[SCAN_BLK];
    int t = threadIdx.x;
    int base = blockIdx.x * ELEMS_PER_BLOCK + t * 4;
    int c[4]; int s = 0;
    #pragma unroll
    for (int i = 0; i < 4; ++i) { int idx = base + i; c[i] = (idx < N_NODES) ? cnt[idx] : 0; s += c[i]; }
    lds[t] = s;
    __syncthreads();
    for (int off = 1; off < SCAN_BLK; off <<= 1) {
        int add = (t >= off) ? lds[t - off] : 0;
        __syncthreads();
        lds[t] += add;
        __syncthreads();
    }
    int ex = boff[blockIdx.x] + ((t == 0) ? 0 : lds[t - 1]);
    #pragma unroll
    for (int i = 0; i < 4; ++i) {
        int idx = base + i;
        if (idx < N_NODES) { ptr[idx] = ex; ex += c[i]; }
    }
}

__global__ void scatter_edges(const int* __restrict__ erow, const int* __restrict__ ecol,
                              const float* __restrict__ eval_, const int* __restrict__ ptr,
                              int* __restrict__ fill, int2* __restrict__ pairs) {
    int e = blockIdx.x * blockDim.x + threadIdx.x;
    if (e >= NNZ_) return;
    int r = erow[e];
    int pos = ptr[r] + atomicAdd(&fill[r], 1);
    pairs[pos] = make_int2(ecol[e], __float_as_int(eval_[e]));
}

// ---------------- input f32 -> bf16 node-feature copy ----------------

__global__ void cvt_bf16(const float* __restrict__ ue, const float* __restrict__ ie,
                         bf16* __restrict__ ebf) {
    int i = blockIdx.x * blockDim.x + threadIdx.x;          // quad index
    const int NQ = N_NODES * DIM / 4;
    if (i >= NQ) return;
    const int UQ = NUM_USERS * DIM / 4;
    float4 v = (i < UQ) ? ((const float4*)ue)[i] : ((const float4*)ie)[i - UQ];
    bf16 o[4] = { __float2bfloat16(v.x), __float2bfloat16(v.y),
                  __float2bfloat16(v.z), __float2bfloat16(v.w) };
    *(ulong1*)(ebf + (size_t)i * 4) = *(ulong1*)o;          // 8 B store
}

// ---------------- CSR SpMM: one wave per row, 8-wide MLP, bf16 storage ----------------

__global__ void spmm_csr(const int* __restrict__ ptr, const int2* __restrict__ pairs,
                         const bf16* __restrict__ x, bf16* __restrict__ out) {
    int w    = (blockIdx.x * blockDim.x + threadIdx.x) >> 6;
    int lane = threadIdx.x & 63;
    if (w >= N_NODES) return;
    int beg = ptr[w], end = ptr[w + 1];
    float a0 = 0.f, a1 = 0.f, a2 = 0.f, a3 = 0.f;
    int e = beg;
    for (; e + 8 <= end; e += 8) {
        int2 p[8];
        #pragma unroll
        for (int k = 0; k < 8; ++k) p[k] = pairs[e + k];
        float xv[8];
        #pragma unroll
        for (int k = 0; k < 8; ++k)
            xv[k] = __bfloat162float(x[(size_t)p[k].x * DIM + lane]);
        a0 = fmaf(__int_as_float(p[0].y), xv[0], a0);
        a1 = fmaf(__int_as_float(p[1].y), xv[1], a1);
        a2 = fmaf(__int_as_float(p[2].y), xv[2], a2);
        a3 = fmaf(__int_as_float(p[3].y), xv[3], a3);
        a0 = fmaf(__int_as_float(p[4].y), xv[4], a0);
        a1 = fmaf(__int_as_float(p[5].y), xv[5], a1);
        a2 = fmaf(__int_as_float(p[6].y), xv[6], a2);
        a3 = fmaf(__int_as_float(p[7].y), xv[7], a3);
    }
    for (; e < end; ++e) {
        int2 p = pairs[e];
        a0 = fmaf(__int_as_float(p.y), __bfloat162float(x[(size_t)p.x * DIM + lane]), a0);
    }
    float acc = (a0 + a1) + (a2 + a3);
    out[(size_t)w * DIM + lane] = __float2bfloat16(acc);
}

// ---------------- BPR loss scoring ----------------

__device__ __forceinline__ float emb0(const float* __restrict__ ue,
                                      const float* __restrict__ ie,
                                      int node, int lane) {
    return (node < NUM_USERS) ? ue[(size_t)node * DIM + lane]
                              : ie[(size_t)(node - NUM_USERS) * DIM + lane];
}

__global__ void score_kernel(const float* __restrict__ ue, const float* __restrict__ ie,
                             const bf16* __restrict__ b0, const bf16* __restrict__ b1,
                             const bf16* __restrict__ b2,
                             const int* __restrict__ users, const int* __restrict__ items,
                             const int* __restrict__ negs,
                             float* __restrict__ out) {
    int t = blockIdx.x * blockDim.x + threadIdx.x;
    int b    = t >> 6;
    int lane = t & 63;
    if (b >= BATCH_) return;

    int un  = users[b];
    int in_ = NUM_USERS + items[b];
    int nn  = NUM_USERS + negs[b];

    size_t ou = (size_t)un  * DIM + lane;
    size_t oi = (size_t)in_ * DIM + lane;
    size_t on = (size_t)nn  * DIM + lane;
    float u  = emb0(ue, ie, un,  lane) + __bfloat162float(b0[ou]) +
               __bfloat162float(b1[ou]) + __bfloat162float(b2[ou]);
    float it = emb0(ue, ie, in_, lane) + __bfloat162float(b0[oi]) +
               __bfloat162float(b1[oi]) + __bfloat162float(b2[oi]);
    float ng = emb0(ue, ie, nn,  lane) + __bfloat162float(b0[on]) +
               __bfloat162float(b1[on]) + __bfloat162float(b2[on]);

    float pos = u * it;
    float neg = u * ng;
    #pragma unroll
    for (int s = 32; s >= 1; s >>= 1) {
        pos += __shfl_xor(pos, s);
        neg += __shfl_xor(neg, s);
    }

    if (lane == 0) {
        float x = (neg - pos) * (1.0f / 16.0f);      // light_out = acc/4 -> dot/16
        float sp = fmaxf(x, 0.0f) + log1pf(expf(-fabsf(x)));
        atomicAdd(out, sp * (1.0f / BATCH_));
    }
}

// ---------------- launch ----------------

extern "C" void kernel_launch(void* const* d_in, const int* in_sizes, int n_in,
                              void* d_out, int out_size, void* d_ws, size_t ws_size,
                              hipStream_t stream) {
    const int*   edge_row  = (const int*)d_in[0];
    const int*   edge_col  = (const int*)d_in[1];
    const float* edge_val  = (const float*)d_in[2];
    const float* user_emb  = (const float*)d_in[3];
    const float* item_emb  = (const float*)d_in[4];
    const int*   users     = (const int*)d_in[5];
    const int*   items     = (const int*)d_in[6];
    const int*   negatives = (const int*)d_in[7];
    float* out = (float*)d_out;

    // workspace layout (4-byte units)
    int* w = (int*)d_ws;
    int*  ptr  = w;                                  // 150002
    int*  cnt  = ptr  + 150002;                      // N
    int*  fill = cnt  + N_NODES;                     // N
    int*  bsum = fill + N_NODES;                     // 256
    int*  boff = bsum + 256;                         // 256
    int2* pairs = (int2*)(boff + 256);               // NNZ int2 (25.6 MB)
    bf16* ebf = (bf16*)(pairs + NNZ_);               // N*64 bf16 (19.2 MB)
    bf16* b0  = ebf + (size_t)N_NODES * DIM;
    bf16* b1  = b0  + (size_t)N_NODES * DIM;
    bf16* b2  = b1  + (size_t)N_NODES * DIM;

    hipMemsetAsync(cnt, 0, 2 * (size_t)N_NODES * sizeof(int), stream);
    hipMemsetAsync(d_out, 0, sizeof(float), stream);

    const int blk = 256;
    const int edgeBlocks = (NNZ_ + blk - 1) / blk;            // 12500
    const int rowWaveBlocks = (N_NODES * 64 + blk - 1) / blk; // 37500
    const int cvtBlocks = (N_NODES * DIM / 4 + blk - 1) / blk;

    hist_rows   <<<edgeBlocks, blk, 0, stream>>>(edge_row, cnt);
    scan_pass1  <<<NBLK_SCAN, SCAN_BLK, 0, stream>>>(cnt, bsum);
    scan_pass2  <<<1, SCAN_BLK, 0, stream>>>(bsum, boff, ptr);
    scan_pass3  <<<NBLK_SCAN, SCAN_BLK, 0, stream>>>(cnt, boff, ptr);
    scatter_edges<<<edgeBlocks, blk, 0, stream>>>(edge_row, edge_col, edge_val, ptr, fill, pairs);
    cvt_bf16    <<<cvtBlocks, blk, 0, stream>>>(user_emb, item_emb, ebf);

    spmm_csr<<<rowWaveBlocks, blk, 0, stream>>>(ptr, pairs, ebf, b0);
    spmm_csr<<<rowWaveBlocks, blk, 0, stream>>>(ptr, pairs, b0, b1);
    spmm_csr<<<rowWaveBlocks, blk, 0, stream>>>(ptr, pairs, b1, b2);

    score_kernel<<<(BATCH_ * 64) / blk, blk, 0, stream>>>(user_emb, item_emb, b0, b1, b2,
                                                          users, items, negatives, out);
}